// Round 1
// baseline (883.592 us; speedup 1.0000x reference)
//
#include <hip/hip_runtime.h>
#include <math.h>

// HGCN conv layer: hyp_linear -> hyp_agg -> hyp_act, fp32 baseline.
// N=8192, IN=512, OUT=128. Three fused GEMM+epilogue dispatches plus a tiny
// weight-prep kernel. All hyperbolic tails are row-wise (norms/dots over the
// 128-wide output row), done in-epilogue with 8-lane shuffle reductions.

#define MINN 1e-15f

__device__ __forceinline__ float artanh_clip(float z) {
  const float B = (float)(1.0 - 1e-7);   // same fp32 clip bound as jnp.clip
  z = fminf(fmaxf(z, -B), B);
  return 0.5f * logf((1.0f + z) / (1.0f - z));
}

// sum across aligned 8-lane group
__device__ __forceinline__ float red8(float v) {
  v += __shfl_xor(v, 1, 8);
  v += __shfl_xor(v, 2, 8);
  v += __shfl_xor(v, 4, 8);
  return v;
}

__device__ __forceinline__ int red8_and(int v) {
  v &= __shfl_xor(v, 1, 8);
  v &= __shfl_xor(v, 2, 8);
  v &= __shfl_xor(v, 4, 8);
  return v;
}

__device__ __forceinline__ float block_reduce_128(float v, float* red, int t) {
  #pragma unroll
  for (int m = 1; m < 64; m <<= 1) v += __shfl_xor(v, m, 64);
  if ((t & 63) == 0) red[t >> 6] = v;
  __syncthreads();
  return red[0] + red[1];
}

// ---------------------------------------------------------------------------
// prep: hw1T[k][o] = proj(expmap0(lin_weight,c),c) transposed   (512x128)
//       hw2T[k][o] = proj(expmap0(agg_weight,c),c) transposed   (128x128)
//       hb[o]      = proj(expmap0(lin_bias,c),c)                (128)
// ---------------------------------------------------------------------------
__global__ __launch_bounds__(128) void prep_kernel(
    const float* __restrict__ lw, const float* __restrict__ aw,
    const float* __restrict__ lb, const float* __restrict__ cp,
    float* __restrict__ hw1T, float* __restrict__ hw2T, float* __restrict__ hb)
{
  const float c  = cp[0];
  const float sc = sqrtf(c);
  const float maxn = 0.996f / sc;            // (1 - 4e-3)/sqrt(c)
  const int b = blockIdx.x, t = threadIdx.x;
  __shared__ float red[2];

  if (b < 128) {                             // lin_weight row b (512 elems)
    float4 v = ((const float4*)(lw + (size_t)b * 512))[t];
    float ss = block_reduce_128(v.x*v.x + v.y*v.y + v.z*v.z + v.w*v.w, red, t);
    float un = fmaxf(sqrtf(ss), MINN);
    float f  = tanhf(sc * un) / (sc * un);   // expmap0 scale
    float nn = f * un;                       // norm of expmap0 result
    if (nn > maxn) f *= maxn / nn;           // proj
    hw1T[(size_t)(4*t+0)*128 + b] = f * v.x;
    hw1T[(size_t)(4*t+1)*128 + b] = f * v.y;
    hw1T[(size_t)(4*t+2)*128 + b] = f * v.z;
    hw1T[(size_t)(4*t+3)*128 + b] = f * v.w;
  } else if (b < 256) {                      // agg_weight row (128 elems)
    int r = b - 128;
    float v = aw[(size_t)r * 128 + t];
    float ss = block_reduce_128(v * v, red, t);
    float un = fmaxf(sqrtf(ss), MINN);
    float f  = tanhf(sc * un) / (sc * un);
    float nn = f * un;
    if (nn > maxn) f *= maxn / nn;
    hw2T[(size_t)t * 128 + r] = f * v;
  } else {                                   // lin_bias (zeros, but general)
    float v = lb[t];
    float ss = block_reduce_128(v * v, red, t);
    float un = fmaxf(sqrtf(ss), MINN);
    float f  = tanhf(sc * un) / (sc * un);
    float nn = f * un;
    if (nn > maxn) f *= maxn / nn;
    hb[t] = f * v;
  }
}

// ---------------------------------------------------------------------------
// Fused GEMM (C = A @ B, B stored [K][128]) + hyperbolic epilogue.
// Block: 32 rows x 128 cols, 256 threads, 4x4 microtile per thread.
// A row sum-of-squares accumulated during staging (full row per block).
// MODE 1: hyp_linear tail  -> h        (A=x,   y=hb)
// MODE 2: support tail     -> support  (A=h)
// MODE 3: hyp_agg+act tail -> out      (A=adj, y=agg_bias)
// ---------------------------------------------------------------------------
template <int MODE>
__global__ __launch_bounds__(256) void hyp_gemm(
    const float* __restrict__ A, const float* __restrict__ B, int K,
    const float* __restrict__ cp, const float* __restrict__ yvec,
    float* __restrict__ out)
{
  __shared__ float a_lds[2][32][36];     // [k][row], pad 36 keeps b128 align
  __shared__ float b_lds[2][32 * 128];   // [k][col]
  const int t    = threadIdx.x;
  const int row0 = blockIdx.x * 32;
  const int ct = t & 31, rt = t >> 5;    // compute microtile coords
  const int ar = t >> 3, aj = t & 7;     // A staging: row ar, k-slot aj*4
  const float c  = cp[0];
  const float sc = sqrtf(c);
  const float maxn = 0.996f / sc;

  float acc[4][4] = {};
  float asum = 0.f;                       // partial ||A_row||^2
  const int nsteps = K >> 5;
  const float* Aptr = A + (size_t)(row0 + ar) * K + aj * 4;
  const float4* Bg  = (const float4*)B;

  // ---- stage tile 0
  float4 aR = *(const float4*)Aptr;
  float4 bR[4];
  #pragma unroll
  for (int i = 0; i < 4; ++i) bR[i] = Bg[t + 256 * i];
  {
    const int k0 = aj * 4;
    a_lds[0][k0+0][ar] = aR.x; a_lds[0][k0+1][ar] = aR.y;
    a_lds[0][k0+2][ar] = aR.z; a_lds[0][k0+3][ar] = aR.w;
    asum += aR.x*aR.x + aR.y*aR.y + aR.z*aR.z + aR.w*aR.w;
    float4* bl = (float4*)&b_lds[0][0];
    #pragma unroll
    for (int i = 0; i < 4; ++i) bl[t + 256 * i] = bR[i];
  }
  __syncthreads();

  int cur = 0;
  for (int s = 0; s < nsteps; ++s) {
    const bool more = (s + 1 < nsteps);
    float4 aN, bN[4];
    if (more) {                           // register prefetch of next tile
      aN = *(const float4*)(Aptr + (size_t)(s + 1) * 32);
      #pragma unroll
      for (int i = 0; i < 4; ++i)
        bN[i] = Bg[(size_t)(s + 1) * 1024 + t + 256 * i];
    }
    #pragma unroll
    for (int k = 0; k < 32; ++k) {
      float4 b4 = *(const float4*)&b_lds[cur][k * 128 + 4 * ct];
      float4 a4 = *(const float4*)&a_lds[cur][k][4 * rt];
      float av[4] = {a4.x, a4.y, a4.z, a4.w};
      float bv[4] = {b4.x, b4.y, b4.z, b4.w};
      #pragma unroll
      for (int r = 0; r < 4; ++r)
        #pragma unroll
        for (int q = 0; q < 4; ++q) acc[r][q] += av[r] * bv[q];
    }
    if (more) {
      const int nx = cur ^ 1;
      const int k0 = aj * 4;
      a_lds[nx][k0+0][ar] = aN.x; a_lds[nx][k0+1][ar] = aN.y;
      a_lds[nx][k0+2][ar] = aN.z; a_lds[nx][k0+3][ar] = aN.w;
      asum += aN.x*aN.x + aN.y*aN.y + aN.z*aN.z + aN.w*aN.w;
      float4* bl = (float4*)&b_lds[nx][0];
      #pragma unroll
      for (int i = 0; i < 4; ++i) bl[t + 256 * i] = bN[i];
      cur = nx;
    }
    __syncthreads();                      // one barrier per K-step
  }

  // ---- epilogue: redistribute mx to row-major LDS, 8 threads per row
  float* mx_lds = &b_lds[0][0];
  #pragma unroll
  for (int r = 0; r < 4; ++r)
    *((float4*)&mx_lds[(4 * rt + r) * 128 + 4 * ct]) =
        make_float4(acc[r][0], acc[r][1], acc[r][2], acc[r][3]);
  __syncthreads();

  const int row = t >> 3, j = t & 7;      // same 8-lane grouping as staging
  float v[16];
  #pragma unroll
  for (int i = 0; i < 4; ++i) {
    float4 q = *((const float4*)&mx_lds[row * 128 + j * 16 + 4 * i]);
    v[4*i+0] = q.x; v[4*i+1] = q.y; v[4*i+2] = q.z; v[4*i+3] = q.w;
  }
  float mxss_l = 0.f; int zf = 1;
  #pragma unroll
  for (int i = 0; i < 16; ++i) { mxss_l += v[i] * v[i]; zf &= (v[i] == 0.f); }
  const float mxss = red8(mxss_l);
  const float xss  = red8(asum);          // ||A_row||^2 (partials match group)
  zf = red8_and(zf);

  const float xn  = fmaxf(sqrtf(xss), MINN);
  const float mxn = fmaxf(sqrtf(mxss), MINN);
  float f1 = 0.f;
  if (!zf) f1 = tanhf(mxn / xn * artanh_clip(sc * xn)) / (mxn * sc);

  float* orow = out + (size_t)(row0 + row) * 128 + j * 16;

  if (MODE == 2) {                        // support = _mobius_from_mx only
    #pragma unroll
    for (int i = 0; i < 4; ++i)
      *((float4*)&orow[4 * i]) = make_float4(
          f1 * v[4*i+0], f1 * v[4*i+1], f1 * v[4*i+2], f1 * v[4*i+3]);
    return;
  }

  // load y vector (hb for MODE 1, agg_bias for MODE 3)
  float yv[16];
  #pragma unroll
  for (int i = 0; i < 4; ++i) {
    float4 q = ((const float4*)yvec)[j * 4 + i];
    yv[4*i+0] = q.x; yv[4*i+1] = q.y; yv[4*i+2] = q.z; yv[4*i+3] = q.w;
  }

  float g = f1;
  if (MODE == 1) {                        // proj before mobius_add
    float rn = f1 * mxn;                  // ||res||
    if (rn > maxn) g = f1 * (maxn / rn);
  }

  // mobius_add(g*v, yv, c)
  float xy_l = 0.f, y2_l = 0.f;
  float o16[16];
  #pragma unroll
  for (int i = 0; i < 16; ++i) {
    o16[i] = g * v[i];
    xy_l += o16[i] * yv[i];
    y2_l += yv[i] * yv[i];
  }
  const float xy = red8(xy_l), y2 = red8(y2_l);
  const float x2 = g * g * mxss;
  const float den = fmaxf(1.0f + 2.0f * c * xy + c * c * x2 * y2, MINN);
  const float ca = (1.0f + 2.0f * c * xy + c * y2) / den;
  const float cb = (1.0f - c * x2) / den;
  float h16[16]; float hss_l = 0.f;
  #pragma unroll
  for (int i = 0; i < 16; ++i) {
    h16[i] = ca * o16[i] + cb * yv[i];
    hss_l += h16[i] * h16[i];
  }
  const float hss = red8(hss_l);
  const float hn  = fmaxf(sqrtf(hss), MINN);
  const float s2  = (hn > maxn) ? maxn / hn : 1.0f;   // proj(.,c)

  if (MODE == 1) {                        // h output
    #pragma unroll
    for (int i = 0; i < 4; ++i)
      *((float4*)&orow[4 * i]) = make_float4(
          s2 * h16[4*i+0], s2 * h16[4*i+1], s2 * h16[4*i+2], s2 * h16[4*i+3]);
    return;
  }

  // MODE 3: hyp_act tail: logmap0 -> leaky_relu -> expmap0(c) -> proj(1-c)
  const float pn = fmaxf(s2 * hn, MINN);
  const float lf = artanh_clip(sc * pn) / (pn * sc);
  float xt[16]; float uss_l = 0.f;
  #pragma unroll
  for (int i = 0; i < 16; ++i) {
    float l = lf * (s2 * h16[i]);
    xt[i] = (l >= 0.f) ? l : 0.01f * l;
    uss_l += xt[i] * xt[i];
  }
  const float uss = red8(uss_l);
  const float un  = fmaxf(sqrtf(uss), MINN);
  const float ef  = tanhf(sc * un) / (sc * un);
  // proj with curvature (1-c): norm of result is ef*un analytically
  const float on = ef * un;
  const float maxn2 = 0.996f / sqrtf(1.0f - c);
  const float s3 = (on > maxn2) ? maxn2 / on : 1.0f;
  #pragma unroll
  for (int i = 0; i < 4; ++i)
    *((float4*)&orow[4 * i]) = make_float4(
        s3 * ef * xt[4*i+0], s3 * ef * xt[4*i+1],
        s3 * ef * xt[4*i+2], s3 * ef * xt[4*i+3]);
}

// ---------------------------------------------------------------------------
extern "C" void kernel_launch(void* const* d_in, const int* in_sizes, int n_in,
                              void* d_out, int out_size, void* d_ws, size_t ws_size,
                              hipStream_t stream)
{
  const float* x   = (const float*)d_in[0];   // [8192,512]
  const float* adj = (const float*)d_in[1];   // [8192,8192]
  const float* cp  = (const float*)d_in[2];   // [1]
  const float* lw  = (const float*)d_in[3];   // [128,512]
  const float* lb  = (const float*)d_in[4];   // [128]
  const float* aw  = (const float*)d_in[5];   // [128,128]
  const float* ab  = (const float*)d_in[6];   // [128]
  float* out = (float*)d_out;                 // [8192,128]
  float* ws  = (float*)d_ws;

  float* hw1T = ws;                            // 512*128
  float* hw2T = ws + 65536;                    // 128*128
  float* hb   = ws + 81920;                    // 128
  float* h    = ws + 131072;                   // 8192*128
  float* sup  = ws + 131072 + 1048576;         // 8192*128

  prep_kernel<<<257, 128, 0, stream>>>(lw, aw, lb, cp, hw1T, hw2T, hb);
  hyp_gemm<1><<<256, 256, 0, stream>>>(x,   hw1T, 512,  cp, hb, h);
  hyp_gemm<2><<<256, 256, 0, stream>>>(h,   hw2T, 128,  cp, nullptr, sup);
  hyp_gemm<3><<<256, 256, 0, stream>>>(adj, sup,  8192, cp, ab, out);
}

// Round 2
// 447.453 us; speedup vs baseline: 1.9747x; 1.9747x over previous
//
#include <hip/hip_runtime.h>
#include <math.h>

// HGCN conv: hyp_linear -> hyp_agg -> hyp_act.
// All three GEMMs on bf16 MFMA 16x16x32; A (fp32 in HBM) is cast to bf16
// during LDS staging while fp32 row-sumsq is accumulated for the hyperbolic
// tails. B matrices are pre-swizzled into MFMA B-fragment order (bf16) so
// each B-frag is one 16B global load from L2. Block = 16 rows x 128 cols,
// 256 thr (4 waves), grid 512 -> 2 blocks/CU.

#define MINN 1e-15f

typedef __bf16 bf16x8 __attribute__((ext_vector_type(8)));
typedef float  f32x4  __attribute__((ext_vector_type(4)));

__device__ __forceinline__ unsigned short f2bf(float f) {   // RNE fp32->bf16
  unsigned int u = __float_as_uint(f);
  u += 0x7FFFu + ((u >> 16) & 1u);
  return (unsigned short)(u >> 16);
}

__device__ __forceinline__ float artanh_clip(float z) {
  const float B = (float)(1.0 - 1e-7);
  z = fminf(fmaxf(z, -B), B);
  return 0.5f * logf((1.0f + z) / (1.0f - z));
}

__device__ __forceinline__ float red16(float v) {
  v += __shfl_xor(v, 1, 16);
  v += __shfl_xor(v, 2, 16);
  v += __shfl_xor(v, 4, 16);
  v += __shfl_xor(v, 8, 16);
  return v;
}
__device__ __forceinline__ int red16_and(int v) {
  v &= __shfl_xor(v, 1, 16);
  v &= __shfl_xor(v, 2, 16);
  v &= __shfl_xor(v, 4, 16);
  v &= __shfl_xor(v, 8, 16);
  return v;
}

__device__ __forceinline__ float block_reduce_128(float v, float* red, int t) {
  #pragma unroll
  for (int m = 1; m < 64; m <<= 1) v += __shfl_xor(v, m, 64);
  if ((t & 63) == 0) red[t >> 6] = v;
  __syncthreads();
  return red[0] + red[1];
}

// B-frag element address (in ushorts) for B[k][n], frag grid (kb, n>>4):
//   ((kb*8 + (n>>4))*64 + ((k>>3)&3)*16 + (n&15))*8 + (k&7)
__device__ __forceinline__ size_t bswz(int k, int n) {
  return ((size_t)(((k >> 5) * 8 + (n >> 4)) * 64 + ((k >> 3) & 3) * 16 +
                   (n & 15))) * 8 + (k & 7);
}

// ---------------------------------------------------------------------------
// prep: B1sw = swizzled bf16 of proj(expmap0(lin_weight,c),c)   [512k x 128n]
//       B2sw = swizzled bf16 of proj(expmap0(agg_weight,c),c)   [128k x 128n]
//       hb   = proj(expmap0(lin_bias,c),c) fp32                 [128]
// ---------------------------------------------------------------------------
__global__ __launch_bounds__(128) void prep_kernel(
    const float* __restrict__ lw, const float* __restrict__ aw,
    const float* __restrict__ lb, const float* __restrict__ cp,
    unsigned short* __restrict__ B1, unsigned short* __restrict__ B2,
    float* __restrict__ hb)
{
  const float c  = cp[0];
  const float sc = sqrtf(c);
  const float maxn = 0.996f / sc;
  const int b = blockIdx.x, t = threadIdx.x;
  __shared__ float red[2];

  if (b < 128) {                       // lin_weight row o (512 elems)
    const int o = b;
    float4 v = ((const float4*)(lw + (size_t)o * 512))[t];
    float ss = block_reduce_128(v.x*v.x + v.y*v.y + v.z*v.z + v.w*v.w, red, t);
    float un = fmaxf(sqrtf(ss), MINN);
    float f  = tanhf(sc * un) / (sc * un);
    float nn = f * un;
    if (nn > maxn) f *= maxn / nn;
    float vals[4] = {v.x, v.y, v.z, v.w};
    #pragma unroll
    for (int i = 0; i < 4; ++i)
      B1[bswz(4 * t + i, o)] = f2bf(f * vals[i]);
  } else if (b < 256) {                // agg_weight row n (128 elems)
    const int n = b - 128;
    float v = aw[(size_t)n * 128 + t];
    float ss = block_reduce_128(v * v, red, t);
    float un = fmaxf(sqrtf(ss), MINN);
    float f  = tanhf(sc * un) / (sc * un);
    float nn = f * un;
    if (nn > maxn) f *= maxn / nn;
    B2[bswz(t, n)] = f2bf(f * v);
  } else {                             // lin_bias
    float v = lb[t];
    float ss = block_reduce_128(v * v, red, t);
    float un = fmaxf(sqrtf(ss), MINN);
    float f  = tanhf(sc * un) / (sc * un);
    float nn = f * un;
    if (nn > maxn) f *= maxn / nn;
    hb[t] = f * v;
  }
}

// ---------------------------------------------------------------------------
// Fused MFMA GEMM (C = A @ B) + hyperbolic epilogue.
// A fp32 [M x K] row-major; B pre-swizzled bf16 frags; 16 rows/block.
// MODE 1: hyp_linear tail -> h (fp32)        y = hb
// MODE 2: support tail    -> B3sw (bf16 swizzled frags for GEMM-3)
// MODE 3: hyp_agg+act     -> out (fp32)      y = agg_bias
// ---------------------------------------------------------------------------
template <int MODE>
__global__ __launch_bounds__(256) void hyp_gemm(
    const float* __restrict__ A, const bf16x8* __restrict__ Bf, int K,
    const float* __restrict__ cp, const float* __restrict__ yvec,
    void* __restrict__ outp)
{
  __shared__ unsigned short a_lds[2][16][72];  // 16 rows x 64k bf16, pad 72
  __shared__ float mx_lds[16][132];
  const int t    = threadIdx.x;
  const int row0 = blockIdx.x * 16;
  const int lane = t & 63, w = t >> 6;
  const int quad = lane >> 4, l15 = lane & 15;
  const int srow = t >> 4, skg = t & 15;       // staging: row, k-group
  const float c  = cp[0];
  const float sc = sqrtf(c);
  const float maxn = 0.996f / sc;
  const int nsteps = K >> 6;                   // K-step = 64

  f32x4 acc0 = {0.f, 0.f, 0.f, 0.f};
  f32x4 acc1 = {0.f, 0.f, 0.f, 0.f};
  float asum = 0.f;                            // fp32 partial ||A_row||^2
  const float* Ap = A + (size_t)(row0 + srow) * K + skg * 4;

  // ---- stage tile 0
  {
    float4 aR = *(const float4*)Ap;
    asum += aR.x*aR.x + aR.y*aR.y + aR.z*aR.z + aR.w*aR.w;
    union { unsigned short u[4]; uint2 v2; } pk;
    pk.u[0] = f2bf(aR.x); pk.u[1] = f2bf(aR.y);
    pk.u[2] = f2bf(aR.z); pk.u[3] = f2bf(aR.w);
    *(uint2*)&a_lds[0][srow][skg * 4] = pk.v2;
  }
  __syncthreads();

  int cur = 0;
  for (int s = 0; s < nsteps; ++s) {
    // B frags for this step (kb = 2s, 2s+1; col-tiles 2w, 2w+1), from L2
    const size_t fb = (size_t)(16 * s) * 64 + lane;
    bf16x8 b00 = Bf[fb + (2 * w + 0) * 64];
    bf16x8 b01 = Bf[fb + (2 * w + 1) * 64];
    bf16x8 b10 = Bf[fb + (8 + 2 * w + 0) * 64];
    bf16x8 b11 = Bf[fb + (8 + 2 * w + 1) * 64];

    const bool more = (s + 1 < nsteps);
    float4 aN;
    if (more) aN = *(const float4*)(Ap + (size_t)(s + 1) * 64);

    bf16x8 a0 = *(const bf16x8*)&a_lds[cur][l15][quad * 8];
    bf16x8 a1 = *(const bf16x8*)&a_lds[cur][l15][32 + quad * 8];
    acc0 = __builtin_amdgcn_mfma_f32_16x16x32_bf16(a0, b00, acc0, 0, 0, 0);
    acc1 = __builtin_amdgcn_mfma_f32_16x16x32_bf16(a0, b01, acc1, 0, 0, 0);
    acc0 = __builtin_amdgcn_mfma_f32_16x16x32_bf16(a1, b10, acc0, 0, 0, 0);
    acc1 = __builtin_amdgcn_mfma_f32_16x16x32_bf16(a1, b11, acc1, 0, 0, 0);

    if (more) {
      asum += aN.x*aN.x + aN.y*aN.y + aN.z*aN.z + aN.w*aN.w;
      union { unsigned short u[4]; uint2 v2; } pk;
      pk.u[0] = f2bf(aN.x); pk.u[1] = f2bf(aN.y);
      pk.u[2] = f2bf(aN.z); pk.u[3] = f2bf(aN.w);
      *(uint2*)&a_lds[cur ^ 1][srow][skg * 4] = pk.v2;
      cur ^= 1;
    }
    __syncthreads();
  }

  // ---- epilogue: park C frags in LDS row-major
  #pragma unroll
  for (int r = 0; r < 4; ++r) {
    mx_lds[quad * 4 + r][32 * w + l15]      = acc0[r];
    mx_lds[quad * 4 + r][32 * w + 16 + l15] = acc1[r];
  }
  __syncthreads();

  const int row = t >> 4, j0 = t & 15;   // 16 threads per row (matches asum)
  float v[8];
  {
    float4 q0 = *(const float4*)&mx_lds[row][j0 * 8];
    float4 q1 = *(const float4*)&mx_lds[row][j0 * 8 + 4];
    v[0]=q0.x; v[1]=q0.y; v[2]=q0.z; v[3]=q0.w;
    v[4]=q1.x; v[5]=q1.y; v[6]=q1.z; v[7]=q1.w;
  }
  float mxss_l = 0.f; int zf = 1;
  #pragma unroll
  for (int i = 0; i < 8; ++i) { mxss_l += v[i] * v[i]; zf &= (v[i] == 0.f); }
  const float mxss = red16(mxss_l);
  const float xss  = red16(asum);
  zf = red16_and(zf);

  const float xn  = fmaxf(sqrtf(xss), MINN);
  const float mxn = fmaxf(sqrtf(mxss), MINN);
  float f1 = 0.f;
  if (!zf) f1 = tanhf(mxn / xn * artanh_clip(sc * xn)) / (mxn * sc);

  if (MODE == 2) {   // write support directly as swizzled bf16 B3 frags
    const int k = row0 + row;
    unsigned short* Bo = (unsigned short*)outp;
    const size_t base = ((size_t)(((k >> 5) * 8 + (j0 >> 1)) * 64 +
                         ((k >> 3) & 3) * 16 + 8 * (j0 & 1))) * 8 + (k & 7);
    #pragma unroll
    for (int i = 0; i < 8; ++i)
      Bo[base + (size_t)i * 8] = f2bf(f1 * v[i]);
    return;
  }

  float yv[8];
  {
    float4 q0 = ((const float4*)yvec)[j0 * 2];
    float4 q1 = ((const float4*)yvec)[j0 * 2 + 1];
    yv[0]=q0.x; yv[1]=q0.y; yv[2]=q0.z; yv[3]=q0.w;
    yv[4]=q1.x; yv[5]=q1.y; yv[6]=q1.z; yv[7]=q1.w;
  }

  float g = f1;
  if (MODE == 1) {                       // proj(res, c) before mobius_add
    float rn = f1 * mxn;
    if (rn > maxn) g = f1 * (maxn / rn);
  }

  // mobius_add(g*v, yv, c)
  float xy_l = 0.f, y2_l = 0.f;
  float o8[8];
  #pragma unroll
  for (int i = 0; i < 8; ++i) {
    o8[i] = g * v[i];
    xy_l += o8[i] * yv[i];
    y2_l += yv[i] * yv[i];
  }
  const float xy = red16(xy_l), y2 = red16(y2_l);
  const float x2 = g * g * mxss;
  const float den = fmaxf(1.0f + 2.0f * c * xy + c * c * x2 * y2, MINN);
  const float ca = (1.0f + 2.0f * c * xy + c * y2) / den;
  const float cb = (1.0f - c * x2) / den;
  float h8[8]; float hss_l = 0.f;
  #pragma unroll
  for (int i = 0; i < 8; ++i) {
    h8[i] = ca * o8[i] + cb * yv[i];
    hss_l += h8[i] * h8[i];
  }
  const float hss = red16(hss_l);
  const float hn  = fmaxf(sqrtf(hss), MINN);
  const float s2  = (hn > maxn) ? maxn / hn : 1.0f;   // proj(., c)

  float* orow = (float*)outp + (size_t)(row0 + row) * 128 + j0 * 8;

  if (MODE == 1) {
    float4 o0 = make_float4(s2*h8[0], s2*h8[1], s2*h8[2], s2*h8[3]);
    float4 o1 = make_float4(s2*h8[4], s2*h8[5], s2*h8[6], s2*h8[7]);
    *(float4*)orow = o0; *(float4*)(orow + 4) = o1;
    return;
  }

  // MODE 3: hyp_act: logmap0 -> leaky_relu -> expmap0(c) -> proj(1-c)
  const float pn = fmaxf(s2 * hn, MINN);
  const float lf = artanh_clip(sc * pn) / (pn * sc);
  float xt[8]; float uss_l = 0.f;
  #pragma unroll
  for (int i = 0; i < 8; ++i) {
    float l = lf * (s2 * h8[i]);
    xt[i] = (l >= 0.f) ? l : 0.01f * l;
    uss_l += xt[i] * xt[i];
  }
  const float uss = red16(uss_l);
  const float un  = fmaxf(sqrtf(uss), MINN);
  const float ef  = tanhf(sc * un) / (sc * un);
  const float on  = ef * un;
  const float maxn2 = 0.996f / sqrtf(1.0f - c);
  const float s3 = (on > maxn2) ? maxn2 / on : 1.0f;
  float4 o0 = make_float4(s3*ef*xt[0], s3*ef*xt[1], s3*ef*xt[2], s3*ef*xt[3]);
  float4 o1 = make_float4(s3*ef*xt[4], s3*ef*xt[5], s3*ef*xt[6], s3*ef*xt[7]);
  *(float4*)orow = o0; *(float4*)(orow + 4) = o1;
}

// ---------------------------------------------------------------------------
extern "C" void kernel_launch(void* const* d_in, const int* in_sizes, int n_in,
                              void* d_out, int out_size, void* d_ws, size_t ws_size,
                              hipStream_t stream)
{
  const float* x   = (const float*)d_in[0];   // [8192,512]
  const float* adj = (const float*)d_in[1];   // [8192,8192]
  const float* cp  = (const float*)d_in[2];   // [1]
  const float* lw  = (const float*)d_in[3];   // [128,512]
  const float* lb  = (const float*)d_in[4];   // [128]
  const float* aw  = (const float*)d_in[5];   // [128,128]
  const float* ab  = (const float*)d_in[6];   // [128]
  float* out = (float*)d_out;                 // [8192,128] fp32

  char* ws = (char*)d_ws;
  unsigned short* B1sw = (unsigned short*)(ws);                  // 128 KiB
  unsigned short* B2sw = (unsigned short*)(ws + 131072);         // 32 KiB
  unsigned short* B3sw = (unsigned short*)(ws + 163840);         // 2 MiB
  float*          hb   = (float*)(ws + 2260992);                 // 512 B
  float*          h    = (float*)(ws + 2261504);                 // 4 MiB

  prep_kernel<<<257, 128, 0, stream>>>(lw, aw, lb, cp, B1sw, B2sw, hb);
  hyp_gemm<1><<<512, 256, 0, stream>>>(x,   (const bf16x8*)B1sw, 512,  cp, hb, h);
  hyp_gemm<2><<<512, 256, 0, stream>>>(h,   (const bf16x8*)B2sw, 128,  cp, nullptr, B3sw);
  hyp_gemm<3><<<512, 256, 0, stream>>>(adj, (const bf16x8*)B3sw, 8192, cp, ab, out);
}

// Round 3
// 438.023 us; speedup vs baseline: 2.0172x; 1.0215x over previous
//
#include <hip/hip_runtime.h>
#include <math.h>

// HGCN conv: hyp_linear -> hyp_agg -> hyp_act.
// All GEMMs on bf16 MFMA 16x16x32, barrier-free K-loop:
//   block = 256 thr = 4 waves, 16 rows/block, K SPLIT across waves (wave w
//   owns k in [w*K/4,(w+1)*K/4)). Each wave computes the full 16x128 C tile
//   over its K slice: A loaded global->register (fp32, squared for row norms,
//   packed to bf16 in-register), B pre-swizzled bf16 frags register-prefetched
//   one step ahead, 8 MFMAs per 32-K step, NO __syncthreads in the loop.
// Single end-of-kernel barrier to sum the 4 partial C tiles + row norms in
// LDS, then the row-wise hyperbolic tail (16 threads per row).

#define MINN 1e-15f

typedef __bf16 bf16x8 __attribute__((ext_vector_type(8)));
typedef float  f32x4  __attribute__((ext_vector_type(4)));

__device__ __forceinline__ unsigned short f2bf(float f) {   // RNE fp32->bf16
  unsigned int u = __float_as_uint(f);
  u += 0x7FFFu + ((u >> 16) & 1u);
  return (unsigned short)(u >> 16);
}

__device__ __forceinline__ float artanh_clip(float z) {
  const float B = (float)(1.0 - 1e-7);
  z = fminf(fmaxf(z, -B), B);
  return 0.5f * logf((1.0f + z) / (1.0f - z));
}

__device__ __forceinline__ float red16(float v) {
  v += __shfl_xor(v, 1, 16);
  v += __shfl_xor(v, 2, 16);
  v += __shfl_xor(v, 4, 16);
  v += __shfl_xor(v, 8, 16);
  return v;
}
__device__ __forceinline__ int red16_and(int v) {
  v &= __shfl_xor(v, 1, 16);
  v &= __shfl_xor(v, 2, 16);
  v &= __shfl_xor(v, 4, 16);
  v &= __shfl_xor(v, 8, 16);
  return v;
}

__device__ __forceinline__ float block_reduce_128(float v, float* red, int t) {
  #pragma unroll
  for (int m = 1; m < 64; m <<= 1) v += __shfl_xor(v, m, 64);
  if ((t & 63) == 0) red[t >> 6] = v;
  __syncthreads();
  return red[0] + red[1];
}

// B-frag element address (ushorts) for B[k][n]:
//   ((k>>5)*8 + (n>>4))*64 + ((k>>3)&3)*16 + (n&15), *8 + (k&7)
__device__ __forceinline__ size_t bswz(int k, int n) {
  return ((size_t)(((k >> 5) * 8 + (n >> 4)) * 64 + ((k >> 3) & 3) * 16 +
                   (n & 15))) * 8 + (k & 7);
}

// ---------------------------------------------------------------------------
__global__ __launch_bounds__(128) void prep_kernel(
    const float* __restrict__ lw, const float* __restrict__ aw,
    const float* __restrict__ lb, const float* __restrict__ cp,
    unsigned short* __restrict__ B1, unsigned short* __restrict__ B2,
    float* __restrict__ hb)
{
  const float c  = cp[0];
  const float sc = sqrtf(c);
  const float maxn = 0.996f / sc;
  const int b = blockIdx.x, t = threadIdx.x;
  __shared__ float red[2];

  if (b < 128) {                       // lin_weight row o (512 elems)
    const int o = b;
    float4 v = ((const float4*)(lw + (size_t)o * 512))[t];
    float ss = block_reduce_128(v.x*v.x + v.y*v.y + v.z*v.z + v.w*v.w, red, t);
    float un = fmaxf(sqrtf(ss), MINN);
    float f  = tanhf(sc * un) / (sc * un);
    float nn = f * un;
    if (nn > maxn) f *= maxn / nn;
    float vals[4] = {v.x, v.y, v.z, v.w};
    #pragma unroll
    for (int i = 0; i < 4; ++i)
      B1[bswz(4 * t + i, o)] = f2bf(f * vals[i]);
  } else if (b < 256) {                // agg_weight row n (128 elems)
    const int n = b - 128;
    float v = aw[(size_t)n * 128 + t];
    float ss = block_reduce_128(v * v, red, t);
    float un = fmaxf(sqrtf(ss), MINN);
    float f  = tanhf(sc * un) / (sc * un);
    float nn = f * un;
    if (nn > maxn) f *= maxn / nn;
    B2[bswz(t, n)] = f2bf(f * v);
  } else {                             // lin_bias
    float v = lb[t];
    float ss = block_reduce_128(v * v, red, t);
    float un = fmaxf(sqrtf(ss), MINN);
    float f  = tanhf(sc * un) / (sc * un);
    float nn = f * un;
    if (nn > maxn) f *= maxn / nn;
    hb[t] = f * v;
  }
}

// ---------------------------------------------------------------------------
// MODE 1: hyp_linear tail -> h (fp32)            y = hb
// MODE 2: support tail    -> B3sw (bf16 frags)
// MODE 3: hyp_agg+act     -> out (fp32)          y = agg_bias
// ---------------------------------------------------------------------------
template <int MODE>
__global__ __launch_bounds__(256, 2) void hyp_gemm(
    const float* __restrict__ A, const bf16x8* __restrict__ Bf, int K,
    const float* __restrict__ cp, const float* __restrict__ yvec,
    void* __restrict__ outp)
{
  __shared__ float part[4][16][132];     // per-wave C partials (pad 132)
  __shared__ float asw[4][16];           // per-wave row-sumsq partials
  const int t    = threadIdx.x;
  const int w    = t >> 6, lane = t & 63;
  const int quad = lane >> 4, l15 = lane & 15;
  const int row0 = blockIdx.x * 16;
  const float c  = cp[0];
  const float sc = sqrtf(c);
  const float maxn = 0.996f / sc;

  const int Kw     = K >> 2;             // this wave's K slice
  const int nsteps = Kw >> 5;            // 32-K steps
  const int k0w    = w * Kw;

  f32x4 acc[8] = {};
  float asum = 0.f;

  const float*  Ap = A + (size_t)(row0 + l15) * K + k0w + quad * 8;
  const bf16x8* Bp = Bf + (size_t)(k0w >> 5) * 512 + lane;

  // prefetch step 0
  float4 a0 = *(const float4*)(Ap);
  float4 a1 = *(const float4*)(Ap + 4);
  bf16x8 b[8];
  #pragma unroll
  for (int i = 0; i < 8; ++i) b[i] = Bp[i * 64];

  for (int s = 0; s < nsteps; ++s) {
    float4 na0, na1; bf16x8 nb[8];
    const bool more = (s + 1 < nsteps);
    if (more) {                          // register prefetch, 1 step ahead
      const float* Ap2 = Ap + (size_t)(s + 1) * 32;
      na0 = *(const float4*)(Ap2);
      na1 = *(const float4*)(Ap2 + 4);
      const bf16x8* Bp2 = Bp + (size_t)(s + 1) * 512;
      #pragma unroll
      for (int i = 0; i < 8; ++i) nb[i] = Bp2[i * 64];
    }
    asum += a0.x*a0.x + a0.y*a0.y + a0.z*a0.z + a0.w*a0.w
          + a1.x*a1.x + a1.y*a1.y + a1.z*a1.z + a1.w*a1.w;
    union { unsigned short u[8]; bf16x8 v; } pk;
    pk.u[0] = f2bf(a0.x); pk.u[1] = f2bf(a0.y);
    pk.u[2] = f2bf(a0.z); pk.u[3] = f2bf(a0.w);
    pk.u[4] = f2bf(a1.x); pk.u[5] = f2bf(a1.y);
    pk.u[6] = f2bf(a1.z); pk.u[7] = f2bf(a1.w);
    #pragma unroll
    for (int i = 0; i < 8; ++i)
      acc[i] = __builtin_amdgcn_mfma_f32_16x16x32_bf16(pk.v, b[i], acc[i],
                                                       0, 0, 0);
    if (more) {
      a0 = na0; a1 = na1;
      #pragma unroll
      for (int i = 0; i < 8; ++i) b[i] = nb[i];
    }
  }

  // ---- wave-local reductions, then one block barrier
  asum += __shfl_xor(asum, 16, 64);      // sum the 4 k-quads -> full slice
  asum += __shfl_xor(asum, 32, 64);
  #pragma unroll
  for (int i = 0; i < 8; ++i)
    #pragma unroll
    for (int r = 0; r < 4; ++r)
      part[w][quad * 4 + r][i * 16 + l15] = acc[i][r];
  if (lane < 16) asw[w][l15] = asum;
  __syncthreads();

  const int row = t >> 4, j0 = t & 15;   // 16 threads per row
  float v[8];
  #pragma unroll
  for (int i = 0; i < 8; ++i)
    v[i] = part[0][row][j0 * 8 + i] + part[1][row][j0 * 8 + i]
         + part[2][row][j0 * 8 + i] + part[3][row][j0 * 8 + i];
  const float xss = asw[0][row] + asw[1][row] + asw[2][row] + asw[3][row];

  float mxss_l = 0.f; int zf = 1;
  #pragma unroll
  for (int i = 0; i < 8; ++i) { mxss_l += v[i] * v[i]; zf &= (v[i] == 0.f); }
  const float mxss = red16(mxss_l);
  zf = red16_and(zf);

  const float xn  = fmaxf(sqrtf(xss), MINN);
  const float mxn = fmaxf(sqrtf(mxss), MINN);
  float f1 = 0.f;
  if (!zf) f1 = tanhf(mxn / xn * artanh_clip(sc * xn)) / (mxn * sc);

  if (MODE == 2) {   // write support as swizzled bf16 B3 frags
    const int k = row0 + row;
    unsigned short* Bo = (unsigned short*)outp;
    const size_t base = ((size_t)(((k >> 5) * 8 + (j0 >> 1)) * 64 +
                         ((k >> 3) & 3) * 16 + 8 * (j0 & 1))) * 8 + (k & 7);
    #pragma unroll
    for (int i = 0; i < 8; ++i)
      Bo[base + (size_t)i * 8] = f2bf(f1 * v[i]);
    return;
  }

  float yv[8];
  {
    float4 q0 = ((const float4*)yvec)[j0 * 2];
    float4 q1 = ((const float4*)yvec)[j0 * 2 + 1];
    yv[0]=q0.x; yv[1]=q0.y; yv[2]=q0.z; yv[3]=q0.w;
    yv[4]=q1.x; yv[5]=q1.y; yv[6]=q1.z; yv[7]=q1.w;
  }

  float g = f1;
  if (MODE == 1) {                       // proj(res, c) before mobius_add
    float rn = f1 * mxn;
    if (rn > maxn) g = f1 * (maxn / rn);
  }

  // mobius_add(g*v, yv, c)
  float xy_l = 0.f, y2_l = 0.f;
  float o8[8];
  #pragma unroll
  for (int i = 0; i < 8; ++i) {
    o8[i] = g * v[i];
    xy_l += o8[i] * yv[i];
    y2_l += yv[i] * yv[i];
  }
  const float xy = red16(xy_l), y2 = red16(y2_l);
  const float x2 = g * g * mxss;
  const float den = fmaxf(1.0f + 2.0f * c * xy + c * c * x2 * y2, MINN);
  const float ca = (1.0f + 2.0f * c * xy + c * y2) / den;
  const float cb = (1.0f - c * x2) / den;
  float h8[8]; float hss_l = 0.f;
  #pragma unroll
  for (int i = 0; i < 8; ++i) {
    h8[i] = ca * o8[i] + cb * yv[i];
    hss_l += h8[i] * h8[i];
  }
  const float hss = red16(hss_l);
  const float hn  = fmaxf(sqrtf(hss), MINN);
  const float s2  = (hn > maxn) ? maxn / hn : 1.0f;   // proj(., c)

  float* orow = (float*)outp + (size_t)(row0 + row) * 128 + j0 * 8;

  if (MODE == 1) {
    float4 o0 = make_float4(s2*h8[0], s2*h8[1], s2*h8[2], s2*h8[3]);
    float4 o1 = make_float4(s2*h8[4], s2*h8[5], s2*h8[6], s2*h8[7]);
    *(float4*)orow = o0; *(float4*)(orow + 4) = o1;
    return;
  }

  // MODE 3: hyp_act: logmap0 -> leaky_relu -> expmap0(c) -> proj(1-c)
  const float pn = fmaxf(s2 * hn, MINN);
  const float lf = artanh_clip(sc * pn) / (pn * sc);
  float xt[8]; float uss_l = 0.f;
  #pragma unroll
  for (int i = 0; i < 8; ++i) {
    float l = lf * (s2 * h8[i]);
    xt[i] = (l >= 0.f) ? l : 0.01f * l;
    uss_l += xt[i] * xt[i];
  }
  const float uss = red16(uss_l);
  const float un  = fmaxf(sqrtf(uss), MINN);
  const float ef  = tanhf(sc * un) / (sc * un);
  const float on  = ef * un;
  const float maxn2 = 0.996f / sqrtf(1.0f - c);
  const float s3 = (on > maxn2) ? maxn2 / on : 1.0f;
  float4 o0 = make_float4(s3*ef*xt[0], s3*ef*xt[1], s3*ef*xt[2], s3*ef*xt[3]);
  float4 o1 = make_float4(s3*ef*xt[4], s3*ef*xt[5], s3*ef*xt[6], s3*ef*xt[7]);
  *(float4*)orow = o0; *(float4*)(orow + 4) = o1;
}

// ---------------------------------------------------------------------------
extern "C" void kernel_launch(void* const* d_in, const int* in_sizes, int n_in,
                              void* d_out, int out_size, void* d_ws, size_t ws_size,
                              hipStream_t stream)
{
  const float* x   = (const float*)d_in[0];   // [8192,512]
  const float* adj = (const float*)d_in[1];   // [8192,8192]
  const float* cp  = (const float*)d_in[2];   // [1]
  const float* lw  = (const float*)d_in[3];   // [128,512]
  const float* lb  = (const float*)d_in[4];   // [128]
  const float* aw  = (const float*)d_in[5];   // [128,128]
  const float* ab  = (const float*)d_in[6];   // [128]
  float* out = (float*)d_out;                 // [8192,128] fp32

  char* ws = (char*)d_ws;
  unsigned short* B1sw = (unsigned short*)(ws);                  // 128 KiB
  unsigned short* B2sw = (unsigned short*)(ws + 131072);         // 32 KiB
  unsigned short* B3sw = (unsigned short*)(ws + 163840);         // 2 MiB
  float*          hb   = (float*)(ws + 2260992);                 // 512 B
  float*          h    = (float*)(ws + 2261504);                 // 4 MiB

  prep_kernel<<<257, 128, 0, stream>>>(lw, aw, lb, cp, B1sw, B2sw, hb);
  hyp_gemm<1><<<512, 256, 0, stream>>>(x,   (const bf16x8*)B1sw, 512,  cp, hb, h);
  hyp_gemm<2><<<512, 256, 0, stream>>>(h,   (const bf16x8*)B2sw, 128,  cp, nullptr, B3sw);
  hyp_gemm<3><<<512, 256, 0, stream>>>(adj, (const bf16x8*)B3sw, 8192, cp, ab, out);
}

// Round 4
// 436.196 us; speedup vs baseline: 2.0257x; 1.0042x over previous
//
#include <hip/hip_runtime.h>
#include <math.h>

// HGCN conv: hyp_linear -> hyp_agg -> hyp_act.
// bf16 MFMA 16x16x32 everywhere, barrier-free K-loops (K split across waves,
// one end-of-kernel barrier to combine partials).
//  - prep:     weights -> hyperbolic, bf16, MFMA-B-fragment-swizzled.
//  - fused12:  h = hyp_linear tail, LDS round-trip, support GEMM (K=128) +
//              tail -> B3 frags. 16 rows/block, grid 512.
//  - gemm3:    adj @ support with 8-deep A / 4-deep B rotating register
//              pipeline (manual x8 unroll, zero copies), v_perm truncation
//              cast for adj, 4-chain row-sumsq. 32 rows/block, grid 256,
//              launch_bounds(256,1) so each wave owns a SIMD (fat VGPRs).

#define MINN 1e-15f

typedef __bf16 bf16x8 __attribute__((ext_vector_type(8)));
typedef float  f32x4  __attribute__((ext_vector_type(4)));

__device__ __forceinline__ unsigned short f2bf(float f) {   // RNE fp32->bf16
  unsigned int u = __float_as_uint(f);
  u += 0x7FFFu + ((u >> 16) & 1u);
  return (unsigned short)(u >> 16);
}

// truncation pack: two fp32 -> packed bf16x2 in ONE v_perm_b32
__device__ __forceinline__ unsigned pk_trunc(float lo, float hi) {
  return __builtin_amdgcn_perm(__float_as_uint(hi), __float_as_uint(lo),
                               0x07060302u);
}

__device__ __forceinline__ float artanh_clip(float z) {
  const float B = (float)(1.0 - 1e-7);
  z = fminf(fmaxf(z, -B), B);
  return 0.5f * logf((1.0f + z) / (1.0f - z));
}

__device__ __forceinline__ float red16(float v) {
  v += __shfl_xor(v, 1, 16);
  v += __shfl_xor(v, 2, 16);
  v += __shfl_xor(v, 4, 16);
  v += __shfl_xor(v, 8, 16);
  return v;
}
__device__ __forceinline__ int red16_and(int v) {
  v &= __shfl_xor(v, 1, 16);
  v &= __shfl_xor(v, 2, 16);
  v &= __shfl_xor(v, 4, 16);
  v &= __shfl_xor(v, 8, 16);
  return v;
}
__device__ __forceinline__ float red8(float v) {
  v += __shfl_xor(v, 1, 8);
  v += __shfl_xor(v, 2, 8);
  v += __shfl_xor(v, 4, 8);
  return v;
}
__device__ __forceinline__ int red8_and(int v) {
  v &= __shfl_xor(v, 1, 8);
  v &= __shfl_xor(v, 2, 8);
  v &= __shfl_xor(v, 4, 8);
  return v;
}

__device__ __forceinline__ float block_reduce_128(float v, float* red, int t) {
  #pragma unroll
  for (int m = 1; m < 64; m <<= 1) v += __shfl_xor(v, m, 64);
  if ((t & 63) == 0) red[t >> 6] = v;
  __syncthreads();
  return red[0] + red[1];
}

// B-frag element address (ushorts) for B[k][n]
__device__ __forceinline__ size_t bswz(int k, int n) {
  return ((size_t)(((k >> 5) * 8 + (n >> 4)) * 64 + ((k >> 3) & 3) * 16 +
                   (n & 15))) * 8 + (k & 7);
}

// ---------------------------------------------------------------------------
__global__ __launch_bounds__(128) void prep_kernel(
    const float* __restrict__ lw, const float* __restrict__ aw,
    const float* __restrict__ lb, const float* __restrict__ cp,
    unsigned short* __restrict__ B1, unsigned short* __restrict__ B2,
    float* __restrict__ hb)
{
  const float c  = cp[0];
  const float sc = sqrtf(c);
  const float maxn = 0.996f / sc;
  const int b = blockIdx.x, t = threadIdx.x;
  __shared__ float red[2];

  if (b < 128) {                       // lin_weight row o (512 elems)
    const int o = b;
    float4 v = ((const float4*)(lw + (size_t)o * 512))[t];
    float ss = block_reduce_128(v.x*v.x + v.y*v.y + v.z*v.z + v.w*v.w, red, t);
    float un = fmaxf(sqrtf(ss), MINN);
    float f  = tanhf(sc * un) / (sc * un);
    float nn = f * un;
    if (nn > maxn) f *= maxn / nn;
    float vals[4] = {v.x, v.y, v.z, v.w};
    #pragma unroll
    for (int i = 0; i < 4; ++i)
      B1[bswz(4 * t + i, o)] = f2bf(f * vals[i]);
  } else if (b < 256) {                // agg_weight row n (128 elems)
    const int n = b - 128;
    float v = aw[(size_t)n * 128 + t];
    float ss = block_reduce_128(v * v, red, t);
    float un = fmaxf(sqrtf(ss), MINN);
    float f  = tanhf(sc * un) / (sc * un);
    float nn = f * un;
    if (nn > maxn) f *= maxn / nn;
    B2[bswz(t, n)] = f2bf(f * v);
  } else {                             // lin_bias
    float v = lb[t];
    float ss = block_reduce_128(v * v, red, t);
    float un = fmaxf(sqrtf(ss), MINN);
    float f  = tanhf(sc * un) / (sc * un);
    float nn = f * un;
    if (nn > maxn) f *= maxn / nn;
    hb[t] = f * v;
  }
}

// ---------------------------------------------------------------------------
// fused hyp_linear + support: x[8192,512] -> h rows (LDS) -> support @ B2
// -> B3 swizzled bf16 frags. 16 rows/block, 256 thr, grid 512.
// ---------------------------------------------------------------------------
__global__ __launch_bounds__(256, 2) void hyp_fused12(
    const float* __restrict__ x, const bf16x8* __restrict__ B1f,
    const bf16x8* __restrict__ B2f, const float* __restrict__ cp,
    const float* __restrict__ hbv, unsigned short* __restrict__ B3)
{
  __shared__ __align__(16) float part[4][16][132];
  __shared__ float asw[4][16];
  __shared__ __align__(16) unsigned short h_lds[16][136];
  const int t = threadIdx.x;
  const int w = t >> 6, lane = t & 63;
  const int quad = lane >> 4, l15 = lane & 15;
  const int row0 = blockIdx.x * 16;
  const float c = cp[0], sc = sqrtf(c), maxn = 0.996f / sc;

  // ---- phase A: mx1 = x @ hw1 (K=512), wave w owns k in [w*128,(w+1)*128)
  f32x4 acc[8] = {};
  float as4[4] = {};
  const float*  Ap = x + (size_t)(row0 + l15) * 512 + w * 128 + quad * 8;
  const bf16x8* Bp = B1f + (size_t)(w * 4) * 512 + lane;

  #pragma unroll
  for (int s = 0; s < 4; ++s) {
    float4 x0 = *(const float4*)(Ap + s * 32);
    float4 x1 = *(const float4*)(Ap + s * 32 + 4);
    as4[0] = fmaf(x0.x, x0.x, fmaf(x0.y, x0.y, as4[0]));
    as4[1] = fmaf(x0.z, x0.z, fmaf(x0.w, x0.w, as4[1]));
    as4[2] = fmaf(x1.x, x1.x, fmaf(x1.y, x1.y, as4[2]));
    as4[3] = fmaf(x1.z, x1.z, fmaf(x1.w, x1.w, as4[3]));
    union { unsigned short us[8]; bf16x8 v; } pk;
    pk.us[0] = f2bf(x0.x); pk.us[1] = f2bf(x0.y);
    pk.us[2] = f2bf(x0.z); pk.us[3] = f2bf(x0.w);
    pk.us[4] = f2bf(x1.x); pk.us[5] = f2bf(x1.y);
    pk.us[6] = f2bf(x1.z); pk.us[7] = f2bf(x1.w);
    #pragma unroll
    for (int i = 0; i < 8; ++i)
      acc[i] = __builtin_amdgcn_mfma_f32_16x16x32_bf16(
                   pk.v, Bp[(size_t)s * 512 + i * 64], acc[i], 0, 0, 0);
  }
  float asum = (as4[0] + as4[1]) + (as4[2] + as4[3]);
  asum += __shfl_xor(asum, 16, 64);
  asum += __shfl_xor(asum, 32, 64);
  #pragma unroll
  for (int i = 0; i < 8; ++i)
    #pragma unroll
    for (int r = 0; r < 4; ++r)
      part[w][quad * 4 + r][i * 16 + l15] = acc[i][r];
  if (lane < 16) asw[w][l15] = asum;
  __syncthreads();

  // ---- tail A: hyp_linear epilogue, 16 threads per row
  const int row = t >> 4, j0 = t & 15;
  float v[8];
  #pragma unroll
  for (int i = 0; i < 8; ++i)
    v[i] = part[0][row][j0 * 8 + i] + part[1][row][j0 * 8 + i]
         + part[2][row][j0 * 8 + i] + part[3][row][j0 * 8 + i];
  const float xss = asw[0][row] + asw[1][row] + asw[2][row] + asw[3][row];

  float mxss_l = 0.f; int zf = 1;
  #pragma unroll
  for (int i = 0; i < 8; ++i) { mxss_l += v[i] * v[i]; zf &= (v[i] == 0.f); }
  const float mxss = red16(mxss_l);
  zf = red16_and(zf);

  const float xn  = fmaxf(sqrtf(xss), MINN);
  const float mxn = fmaxf(sqrtf(mxss), MINN);
  float f1 = 0.f;
  if (!zf) f1 = tanhf(mxn / xn * artanh_clip(sc * xn)) / (mxn * sc);

  float g = f1;
  {                                     // proj(res, c)
    float rn = f1 * mxn;
    if (rn > maxn) g = f1 * (maxn / rn);
  }
  float yv[8];
  {
    float4 q0 = ((const float4*)hbv)[j0 * 2];
    float4 q1 = ((const float4*)hbv)[j0 * 2 + 1];
    yv[0]=q0.x; yv[1]=q0.y; yv[2]=q0.z; yv[3]=q0.w;
    yv[4]=q1.x; yv[5]=q1.y; yv[6]=q1.z; yv[7]=q1.w;
  }
  float xy_l = 0.f, y2_l = 0.f, o8[8];
  #pragma unroll
  for (int i = 0; i < 8; ++i) {
    o8[i] = g * v[i];
    xy_l += o8[i] * yv[i];
    y2_l += yv[i] * yv[i];
  }
  const float xy = red16(xy_l), y2 = red16(y2_l);
  const float x2 = g * g * mxss;
  const float den = fmaxf(1.0f + 2.0f * c * xy + c * c * x2 * y2, MINN);
  const float ca = (1.0f + 2.0f * c * xy + c * y2) / den;
  const float cb = (1.0f - c * x2) / den;
  float h8[8]; float hss_l = 0.f;
  #pragma unroll
  for (int i = 0; i < 8; ++i) {
    h8[i] = ca * o8[i] + cb * yv[i];
    hss_l += h8[i] * h8[i];
  }
  const float hss = red16(hss_l);
  const float hn  = fmaxf(sqrtf(hss), MINN);
  const float s2  = (hn > maxn) ? maxn / hn : 1.0f;   // proj(., c)
  const float hn2 = fmaxf(s2 * hn, MINN);             // ||h row|| exact fp32

  {                                     // h row -> LDS as bf16 (RNE)
    union { unsigned short us[8]; uint4 q; } hp;
    #pragma unroll
    for (int i = 0; i < 8; ++i) hp.us[i] = f2bf(s2 * h8[i]);
    *(uint4*)&h_lds[row][j0 * 8] = hp.q;
  }
  __syncthreads();

  // ---- phase B: support = h @ hw2 (K=128), wave w owns k in [w*32,..)
  const bf16x8 av2 = *(const bf16x8*)&h_lds[l15][w * 32 + quad * 8];
  f32x4 acc2[8] = {};
  #pragma unroll
  for (int i = 0; i < 8; ++i)
    acc2[i] = __builtin_amdgcn_mfma_f32_16x16x32_bf16(
                  av2, B2f[(size_t)(w * 8 + i) * 64 + lane], acc2[i], 0, 0, 0);
  #pragma unroll
  for (int i = 0; i < 8; ++i)
    #pragma unroll
    for (int r = 0; r < 4; ++r)
      part[w][quad * 4 + r][i * 16 + l15] = acc2[i][r];
  __syncthreads();

  // ---- tail B: support epilogue -> B3 swizzled bf16
  float v2[8];
  #pragma unroll
  for (int i = 0; i < 8; ++i)
    v2[i] = part[0][row][j0 * 8 + i] + part[1][row][j0 * 8 + i]
          + part[2][row][j0 * 8 + i] + part[3][row][j0 * 8 + i];
  float m2l = 0.f; int zf2 = 1;
  #pragma unroll
  for (int i = 0; i < 8; ++i) { m2l += v2[i] * v2[i]; zf2 &= (v2[i] == 0.f); }
  const float mx2ss = red16(m2l);
  zf2 = red16_and(zf2);
  const float mx2n = fmaxf(sqrtf(mx2ss), MINN);
  float f2 = 0.f;
  if (!zf2) f2 = tanhf(mx2n / hn2 * artanh_clip(sc * hn2)) / (mx2n * sc);

  const int k = row0 + row;
  const size_t base = ((size_t)(((k >> 5) * 8 + (j0 >> 1)) * 64 +
                       ((k >> 3) & 3) * 16 + 8 * (j0 & 1))) * 8 + (k & 7);
  #pragma unroll
  for (int i = 0; i < 8; ++i)
    B3[base + (size_t)i * 8] = f2bf(f2 * v2[i]);
}

// ---------------------------------------------------------------------------
// gemm3: out = hyp_agg+act( adj @ support ). 32 rows/block, grid 256.
// Wave w: row-half (w>>1), K-half (w&1) of 8192. 128 x 32-K steps.
// ---------------------------------------------------------------------------
#define G3_COMPUTE(U)                                                        \
  {                                                                          \
    float4 x0 = a0[U], x1 = a1[U];                                           \
    as4[0] = fmaf(x0.x, x0.x, fmaf(x0.y, x0.y, as4[0]));                     \
    as4[1] = fmaf(x0.z, x0.z, fmaf(x0.w, x0.w, as4[1]));                     \
    as4[2] = fmaf(x1.x, x1.x, fmaf(x1.y, x1.y, as4[2]));                     \
    as4[3] = fmaf(x1.z, x1.z, fmaf(x1.w, x1.w, as4[3]));                     \
    union { unsigned u32[4]; bf16x8 v; } pk;                                 \
    pk.u32[0] = pk_trunc(x0.x, x0.y);                                        \
    pk.u32[1] = pk_trunc(x0.z, x0.w);                                        \
    pk.u32[2] = pk_trunc(x1.x, x1.y);                                        \
    pk.u32[3] = pk_trunc(x1.z, x1.w);                                        \
    _Pragma("unroll")                                                        \
    for (int i = 0; i < 8; ++i)                                              \
      acc[i] = __builtin_amdgcn_mfma_f32_16x16x32_bf16(pk.v, b[(U) & 3][i],  \
                                                       acc[i], 0, 0, 0);     \
  }

__global__ __launch_bounds__(256, 1) void hyp_gemm3(
    const float* __restrict__ A, const bf16x8* __restrict__ Bf,
    const float* __restrict__ cp, const float* __restrict__ yvec,
    float* __restrict__ out)
{
  __shared__ __align__(16) float part[4][16][132];
  __shared__ float asw[4][16];
  const int t = threadIdx.x;
  const int w = t >> 6, lane = t & 63;
  const int quad = lane >> 4, l15 = lane & 15;
  const int rh = w >> 1, kh = w & 1;
  const int rowbase = blockIdx.x * 32;
  const int row0 = rowbase + rh * 16;
  const float c = cp[0], sc = sqrtf(c), maxn = 0.996f / sc;

  const int k0w = kh * 4096;
  f32x4 acc[8] = {};
  float as4[4] = {};
  const float*  Ap = A + (size_t)(row0 + l15) * 8192 + k0w + quad * 8;
  const bf16x8* Bp = Bf + (size_t)(k0w >> 5) * 512 + lane;

  float4 a0[8], a1[8];
  bf16x8 b[4][8];
  #pragma unroll
  for (int p = 0; p < 8; ++p) {
    a0[p] = *(const float4*)(Ap + p * 32);
    a1[p] = *(const float4*)(Ap + p * 32 + 4);
  }
  #pragma unroll
  for (int p = 0; p < 4; ++p)
    #pragma unroll
    for (int i = 0; i < 8; ++i) b[p][i] = Bp[(size_t)p * 512 + i * 64];

  for (int s = 0; s < 120; s += 8) {           // main: all refills in range
    #pragma unroll
    for (int u = 0; u < 8; ++u) {
      const int sv = s + u;
      G3_COMPUTE(u);
      a0[u] = *(const float4*)(Ap + (size_t)(sv + 8) * 32);
      a1[u] = *(const float4*)(Ap + (size_t)(sv + 8) * 32 + 4);
      #pragma unroll
      for (int i = 0; i < 8; ++i)
        b[u & 3][i] = Bp[(size_t)(sv + 4) * 512 + i * 64];
    }
  }
  #pragma unroll
  for (int u = 0; u < 8; ++u) {                // tail: steps 120..127
    G3_COMPUTE(u);
    if (u < 4) {
      #pragma unroll
      for (int i = 0; i < 8; ++i)
        b[u & 3][i] = Bp[(size_t)(124 + u) * 512 + i * 64];
    }
  }

  float asum = (as4[0] + as4[1]) + (as4[2] + as4[3]);
  asum += __shfl_xor(asum, 16, 64);
  asum += __shfl_xor(asum, 32, 64);
  #pragma unroll
  for (int i = 0; i < 8; ++i)
    #pragma unroll
    for (int r = 0; r < 4; ++r)
      part[w][quad * 4 + r][i * 16 + l15] = acc[i][r];
  if (lane < 16) asw[w][l15] = asum;
  __syncthreads();

  // ---- epilogue: 8 threads per row, 16 cols each
  const int row = t >> 3, j0 = t & 7;
  const int rh2 = row >> 4, rr = row & 15;
  float v[16];
  #pragma unroll
  for (int i = 0; i < 4; ++i) {
    float4 qa = *(const float4*)&part[rh2 * 2][rr][j0 * 16 + 4 * i];
    float4 qb = *(const float4*)&part[rh2 * 2 + 1][rr][j0 * 16 + 4 * i];
    v[4*i+0] = qa.x + qb.x; v[4*i+1] = qa.y + qb.y;
    v[4*i+2] = qa.z + qb.z; v[4*i+3] = qa.w + qb.w;
  }
  const float xss = asw[rh2 * 2][rr] + asw[rh2 * 2 + 1][rr];

  float mxss_l = 0.f; int zf = 1;
  #pragma unroll
  for (int i = 0; i < 16; ++i) { mxss_l += v[i] * v[i]; zf &= (v[i] == 0.f); }
  const float mxss = red8(mxss_l);
  zf = red8_and(zf);

  const float xn  = fmaxf(sqrtf(xss), MINN);
  const float mxn = fmaxf(sqrtf(mxss), MINN);
  float f1 = 0.f;
  if (!zf) f1 = tanhf(mxn / xn * artanh_clip(sc * xn)) / (mxn * sc);

  float yv[16];
  #pragma unroll
  for (int i = 0; i < 4; ++i) {
    float4 q = ((const float4*)yvec)[j0 * 4 + i];
    yv[4*i+0] = q.x; yv[4*i+1] = q.y; yv[4*i+2] = q.z; yv[4*i+3] = q.w;
  }

  // out = mobius_add(f1*v, yv, c)   (raw Euclidean bias per source)
  float xy_l = 0.f, y2_l = 0.f, o16[16];
  #pragma unroll
  for (int i = 0; i < 16; ++i) {
    o16[i] = f1 * v[i];
    xy_l += o16[i] * yv[i];
    y2_l += yv[i] * yv[i];
  }
  const float xy = red8(xy_l), y2 = red8(y2_l);
  const float x2 = f1 * f1 * mxss;
  const float den = fmaxf(1.0f + 2.0f * c * xy + c * c * x2 * y2, MINN);
  const float ca = (1.0f + 2.0f * c * xy + c * y2) / den;
  const float cb = (1.0f - c * x2) / den;
  float h16[16]; float hss_l = 0.f;
  #pragma unroll
  for (int i = 0; i < 16; ++i) {
    h16[i] = ca * o16[i] + cb * yv[i];
    hss_l += h16[i] * h16[i];
  }
  const float hss = red8(hss_l);
  const float hn  = fmaxf(sqrtf(hss), MINN);
  const float s2  = (hn > maxn) ? maxn / hn : 1.0f;   // proj(., c)

  // hyp_act: logmap0 -> leaky_relu -> expmap0(c) -> proj(1-c)
  const float pn = fmaxf(s2 * hn, MINN);
  const float lf = artanh_clip(sc * pn) / (pn * sc);
  float xt[16]; float uss_l = 0.f;
  #pragma unroll
  for (int i = 0; i < 16; ++i) {
    float l = lf * (s2 * h16[i]);
    xt[i] = (l >= 0.f) ? l : 0.01f * l;
    uss_l += xt[i] * xt[i];
  }
  const float uss = red8(uss_l);
  const float un  = fmaxf(sqrtf(uss), MINN);
  const float ef  = tanhf(sc * un) / (sc * un);
  const float on  = ef * un;
  const float maxn2 = 0.996f / sqrtf(1.0f - c);
  const float s3 = (on > maxn2) ? maxn2 / on : 1.0f;

  float* orow = out + (size_t)(rowbase + row) * 128 + j0 * 16;
  #pragma unroll
  for (int i = 0; i < 4; ++i)
    *(float4*)(orow + 4 * i) = make_float4(
        s3 * ef * xt[4*i+0], s3 * ef * xt[4*i+1],
        s3 * ef * xt[4*i+2], s3 * ef * xt[4*i+3]);
}

// ---------------------------------------------------------------------------
extern "C" void kernel_launch(void* const* d_in, const int* in_sizes, int n_in,
                              void* d_out, int out_size, void* d_ws, size_t ws_size,
                              hipStream_t stream)
{
  const float* x   = (const float*)d_in[0];   // [8192,512]
  const float* adj = (const float*)d_in[1];   // [8192,8192]
  const float* cp  = (const float*)d_in[2];   // [1]
  const float* lw  = (const float*)d_in[3];   // [128,512]
  const float* lb  = (const float*)d_in[4];   // [128]
  const float* aw  = (const float*)d_in[5];   // [128,128]
  const float* ab  = (const float*)d_in[6];   // [128]
  float* out = (float*)d_out;                 // [8192,128] fp32

  char* ws = (char*)d_ws;
  unsigned short* B1sw = (unsigned short*)(ws);                  // 128 KiB
  unsigned short* B2sw = (unsigned short*)(ws + 131072);         // 32 KiB
  unsigned short* B3sw = (unsigned short*)(ws + 163840);         // 2 MiB
  float*          hb   = (float*)(ws + 2260992);                 // 512 B

  prep_kernel<<<257, 128, 0, stream>>>(lw, aw, lb, cp, B1sw, B2sw, hb);
  hyp_fused12<<<512, 256, 0, stream>>>(x, (const bf16x8*)B1sw,
                                       (const bf16x8*)B2sw, cp, hb, B3sw);
  hyp_gemm3<<<256, 256, 0, stream>>>(adj, (const bf16x8*)B3sw, cp, ab, out);
}

// Round 5
// 408.254 us; speedup vs baseline: 2.1643x; 1.0684x over previous
//
#include <hip/hip_runtime.h>
#include <math.h>

// HGCN conv: hyp_linear -> hyp_agg -> hyp_act.  bf16 MFMA 16x16x32.
//  - prep:    weights -> hyperbolic, bf16, MFMA-B-frag-swizzled.
//  - fused12: hyp_linear + support GEMM + tails -> B3 frags (16 rows/blk).
//  - gemm3:   adj @ support via CONTIGUOUS lane-major global loads (1 KiB
//             per wave-instruction, one row-chunk) -> bf16 pack -> LDS ->
//             MFMA A-frags. 32 rows x 128 cols per block (512 thr, 8 waves,
//             2 row-groups x 4 col-groups), K-window 256, 1 barrier/window.

#define MINN 1e-15f

typedef __bf16 bf16x8 __attribute__((ext_vector_type(8)));
typedef float  f32x4  __attribute__((ext_vector_type(4)));

__device__ __forceinline__ unsigned short f2bf(float f) {   // RNE fp32->bf16
  unsigned int u = __float_as_uint(f);
  u += 0x7FFFu + ((u >> 16) & 1u);
  return (unsigned short)(u >> 16);
}

// truncation pack: two fp32 -> packed bf16x2 in ONE v_perm_b32
__device__ __forceinline__ unsigned pk_trunc(float lo, float hi) {
  return __builtin_amdgcn_perm(__float_as_uint(hi), __float_as_uint(lo),
                               0x07060302u);
}

__device__ __forceinline__ float artanh_clip(float z) {
  const float B = (float)(1.0 - 1e-7);
  z = fminf(fmaxf(z, -B), B);
  return 0.5f * logf((1.0f + z) / (1.0f - z));
}

__device__ __forceinline__ float red16(float v) {
  v += __shfl_xor(v, 1, 16);
  v += __shfl_xor(v, 2, 16);
  v += __shfl_xor(v, 4, 16);
  v += __shfl_xor(v, 8, 16);
  return v;
}
__device__ __forceinline__ int red16_and(int v) {
  v &= __shfl_xor(v, 1, 16);
  v &= __shfl_xor(v, 2, 16);
  v &= __shfl_xor(v, 4, 16);
  v &= __shfl_xor(v, 8, 16);
  return v;
}

__device__ __forceinline__ float block_reduce_128(float v, float* red, int t) {
  #pragma unroll
  for (int m = 1; m < 64; m <<= 1) v += __shfl_xor(v, m, 64);
  if ((t & 63) == 0) red[t >> 6] = v;
  __syncthreads();
  return red[0] + red[1];
}

// B-frag element address (ushorts) for B[k][n]
__device__ __forceinline__ size_t bswz(int k, int n) {
  return ((size_t)(((k >> 5) * 8 + (n >> 4)) * 64 + ((k >> 3) & 3) * 16 +
                   (n & 15))) * 8 + (k & 7);
}

// ---------------------------------------------------------------------------
__global__ __launch_bounds__(128) void prep_kernel(
    const float* __restrict__ lw, const float* __restrict__ aw,
    const float* __restrict__ lb, const float* __restrict__ cp,
    unsigned short* __restrict__ B1, unsigned short* __restrict__ B2,
    float* __restrict__ hb)
{
  const float c  = cp[0];
  const float sc = sqrtf(c);
  const float maxn = 0.996f / sc;
  const int b = blockIdx.x, t = threadIdx.x;
  __shared__ float red[2];

  if (b < 128) {                       // lin_weight row o (512 elems)
    const int o = b;
    float4 v = ((const float4*)(lw + (size_t)o * 512))[t];
    float ss = block_reduce_128(v.x*v.x + v.y*v.y + v.z*v.z + v.w*v.w, red, t);
    float un = fmaxf(sqrtf(ss), MINN);
    float f  = tanhf(sc * un) / (sc * un);
    float nn = f * un;
    if (nn > maxn) f *= maxn / nn;
    float vals[4] = {v.x, v.y, v.z, v.w};
    #pragma unroll
    for (int i = 0; i < 4; ++i)
      B1[bswz(4 * t + i, o)] = f2bf(f * vals[i]);
  } else if (b < 256) {                // agg_weight row n (128 elems)
    const int n = b - 128;
    float v = aw[(size_t)n * 128 + t];
    float ss = block_reduce_128(v * v, red, t);
    float un = fmaxf(sqrtf(ss), MINN);
    float f  = tanhf(sc * un) / (sc * un);
    float nn = f * un;
    if (nn > maxn) f *= maxn / nn;
    B2[bswz(t, n)] = f2bf(f * v);
  } else {                             // lin_bias
    float v = lb[t];
    float ss = block_reduce_128(v * v, red, t);
    float un = fmaxf(sqrtf(ss), MINN);
    float f  = tanhf(sc * un) / (sc * un);
    float nn = f * un;
    if (nn > maxn) f *= maxn / nn;
    hb[t] = f * v;
  }
}

// ---------------------------------------------------------------------------
// fused hyp_linear + support (unchanged from round 4 — validated).
// ---------------------------------------------------------------------------
__global__ __launch_bounds__(256, 2) void hyp_fused12(
    const float* __restrict__ x, const bf16x8* __restrict__ B1f,
    const bf16x8* __restrict__ B2f, const float* __restrict__ cp,
    const float* __restrict__ hbv, unsigned short* __restrict__ B3)
{
  __shared__ __align__(16) float part[4][16][132];
  __shared__ float asw[4][16];
  __shared__ __align__(16) unsigned short h_lds[16][136];
  const int t = threadIdx.x;
  const int w = t >> 6, lane = t & 63;
  const int quad = lane >> 4, l15 = lane & 15;
  const int row0 = blockIdx.x * 16;
  const float c = cp[0], sc = sqrtf(c), maxn = 0.996f / sc;

  f32x4 acc[8] = {};
  float as4[4] = {};
  const float*  Ap = x + (size_t)(row0 + l15) * 512 + w * 128 + quad * 8;
  const bf16x8* Bp = B1f + (size_t)(w * 4) * 512 + lane;

  #pragma unroll
  for (int s = 0; s < 4; ++s) {
    float4 x0 = *(const float4*)(Ap + s * 32);
    float4 x1 = *(const float4*)(Ap + s * 32 + 4);
    as4[0] = fmaf(x0.x, x0.x, fmaf(x0.y, x0.y, as4[0]));
    as4[1] = fmaf(x0.z, x0.z, fmaf(x0.w, x0.w, as4[1]));
    as4[2] = fmaf(x1.x, x1.x, fmaf(x1.y, x1.y, as4[2]));
    as4[3] = fmaf(x1.z, x1.z, fmaf(x1.w, x1.w, as4[3]));
    union { unsigned short us[8]; bf16x8 v; } pk;
    pk.us[0] = f2bf(x0.x); pk.us[1] = f2bf(x0.y);
    pk.us[2] = f2bf(x0.z); pk.us[3] = f2bf(x0.w);
    pk.us[4] = f2bf(x1.x); pk.us[5] = f2bf(x1.y);
    pk.us[6] = f2bf(x1.z); pk.us[7] = f2bf(x1.w);
    #pragma unroll
    for (int i = 0; i < 8; ++i)
      acc[i] = __builtin_amdgcn_mfma_f32_16x16x32_bf16(
                   pk.v, Bp[(size_t)s * 512 + i * 64], acc[i], 0, 0, 0);
  }
  float asum = (as4[0] + as4[1]) + (as4[2] + as4[3]);
  asum += __shfl_xor(asum, 16, 64);
  asum += __shfl_xor(asum, 32, 64);
  #pragma unroll
  for (int i = 0; i < 8; ++i)
    #pragma unroll
    for (int r = 0; r < 4; ++r)
      part[w][quad * 4 + r][i * 16 + l15] = acc[i][r];
  if (lane < 16) asw[w][l15] = asum;
  __syncthreads();

  const int row = t >> 4, j0 = t & 15;
  float v[8];
  #pragma unroll
  for (int i = 0; i < 8; ++i)
    v[i] = part[0][row][j0 * 8 + i] + part[1][row][j0 * 8 + i]
         + part[2][row][j0 * 8 + i] + part[3][row][j0 * 8 + i];
  const float xss = asw[0][row] + asw[1][row] + asw[2][row] + asw[3][row];

  float mxss_l = 0.f; int zf = 1;
  #pragma unroll
  for (int i = 0; i < 8; ++i) { mxss_l += v[i] * v[i]; zf &= (v[i] == 0.f); }
  const float mxss = red16(mxss_l);
  zf = red16_and(zf);

  const float xn  = fmaxf(sqrtf(xss), MINN);
  const float mxn = fmaxf(sqrtf(mxss), MINN);
  float f1 = 0.f;
  if (!zf) f1 = tanhf(mxn / xn * artanh_clip(sc * xn)) / (mxn * sc);

  float g = f1;
  {
    float rn = f1 * mxn;
    if (rn > maxn) g = f1 * (maxn / rn);
  }
  float yv[8];
  {
    float4 q0 = ((const float4*)hbv)[j0 * 2];
    float4 q1 = ((const float4*)hbv)[j0 * 2 + 1];
    yv[0]=q0.x; yv[1]=q0.y; yv[2]=q0.z; yv[3]=q0.w;
    yv[4]=q1.x; yv[5]=q1.y; yv[6]=q1.z; yv[7]=q1.w;
  }
  float xy_l = 0.f, y2_l = 0.f, o8[8];
  #pragma unroll
  for (int i = 0; i < 8; ++i) {
    o8[i] = g * v[i];
    xy_l += o8[i] * yv[i];
    y2_l += yv[i] * yv[i];
  }
  const float xy = red16(xy_l), y2 = red16(y2_l);
  const float x2 = g * g * mxss;
  const float den = fmaxf(1.0f + 2.0f * c * xy + c * c * x2 * y2, MINN);
  const float ca = (1.0f + 2.0f * c * xy + c * y2) / den;
  const float cb = (1.0f - c * x2) / den;
  float h8[8]; float hss_l = 0.f;
  #pragma unroll
  for (int i = 0; i < 8; ++i) {
    h8[i] = ca * o8[i] + cb * yv[i];
    hss_l += h8[i] * h8[i];
  }
  const float hss = red16(hss_l);
  const float hn  = fmaxf(sqrtf(hss), MINN);
  const float s2  = (hn > maxn) ? maxn / hn : 1.0f;
  const float hn2 = fmaxf(s2 * hn, MINN);

  {
    union { unsigned short us[8]; uint4 q; } hp;
    #pragma unroll
    for (int i = 0; i < 8; ++i) hp.us[i] = f2bf(s2 * h8[i]);
    *(uint4*)&h_lds[row][j0 * 8] = hp.q;
  }
  __syncthreads();

  const bf16x8 av2 = *(const bf16x8*)&h_lds[l15][w * 32 + quad * 8];
  f32x4 acc2[8] = {};
  #pragma unroll
  for (int i = 0; i < 8; ++i)
    acc2[i] = __builtin_amdgcn_mfma_f32_16x16x32_bf16(
                  av2, B2f[(size_t)(w * 8 + i) * 64 + lane], acc2[i], 0, 0, 0);
  #pragma unroll
  for (int i = 0; i < 8; ++i)
    #pragma unroll
    for (int r = 0; r < 4; ++r)
      part[w][quad * 4 + r][i * 16 + l15] = acc2[i][r];
  __syncthreads();

  float v2[8];
  #pragma unroll
  for (int i = 0; i < 8; ++i)
    v2[i] = part[0][row][j0 * 8 + i] + part[1][row][j0 * 8 + i]
          + part[2][row][j0 * 8 + i] + part[3][row][j0 * 8 + i];
  float m2l = 0.f; int zf2 = 1;
  #pragma unroll
  for (int i = 0; i < 8; ++i) { m2l += v2[i] * v2[i]; zf2 &= (v2[i] == 0.f); }
  const float mx2ss = red16(m2l);
  zf2 = red16_and(zf2);
  const float mx2n = fmaxf(sqrtf(mx2ss), MINN);
  float f2 = 0.f;
  if (!zf2) f2 = tanhf(mx2n / hn2 * artanh_clip(sc * hn2)) / (mx2n * sc);

  const int k = row0 + row;
  const size_t base = ((size_t)(((k >> 5) * 8 + (j0 >> 1)) * 64 +
                       ((k >> 3) & 3) * 16 + 8 * (j0 & 1))) * 8 + (k & 7);
  #pragma unroll
  for (int i = 0; i < 8; ++i)
    B3[base + (size_t)i * 8] = f2bf(f2 * v2[i]);
}

// ---------------------------------------------------------------------------
// gemm3: out = hyp_agg+act( adj @ support ).
// 512 thr (8 waves) x 32 rows x 128 cols, grid 256. Waves: wm=w>>2 row-group,
// wn=w&3 col-group (32 cols). Staging: wave w loads rows 4w..4w+3, one
// CONTIGUOUS 1 KiB chunk per instruction (lane-major), packs bf16 -> LDS.
// K-window 256, one barrier per window.
// ---------------------------------------------------------------------------
__global__ __launch_bounds__(512, 2) void hyp_gemm3(
    const float* __restrict__ A, const bf16x8* __restrict__ Bf,
    const float* __restrict__ cp, const float* __restrict__ yvec,
    float* __restrict__ out)
{
  __shared__ __align__(16) unsigned short a_lds[2][32][264];  // 33792 B
  const int t = threadIdx.x;
  const int w = t >> 6, lane = t & 63;
  const int quad = lane >> 4, l15 = lane & 15;
  const int wm = w >> 2, wn = w & 3;
  const int row0 = blockIdx.x * 32;
  const float c = cp[0], sc = sqrtf(c), maxn = 0.996f / sc;

  f32x4 acc[2] = {};
  float as4[4] = {};
  // staging base: wave w, rows 4w..4w+3, lane-major within 256-float window
  const float* Ap = A + (size_t)(row0 + 4 * w) * 8192 + lane * 4;
  const bf16x8* Bw = Bf + (size_t)(2 * wn) * 64 + lane;

  // ---- stage window 0
  {
    float4 aR[4];
    #pragma unroll
    for (int j = 0; j < 4; ++j) aR[j] = *(const float4*)(Ap + j * 8192);
    #pragma unroll
    for (int j = 0; j < 4; ++j) {
      as4[j] = fmaf(aR[j].x, aR[j].x, fmaf(aR[j].y, aR[j].y,
               fmaf(aR[j].z, aR[j].z, fmaf(aR[j].w, aR[j].w, as4[j]))));
      *(uint2*)&a_lds[0][4 * w + j][lane * 4] =
          make_uint2(pk_trunc(aR[j].x, aR[j].y), pk_trunc(aR[j].z, aR[j].w));
    }
  }
  __syncthreads();

  for (int win = 0; win < 32; ++win) {
    const int cur = win & 1;
    // B frags for this window (issued first so MFMA waits don't drain A)
    bf16x8 b[8][2];
    #pragma unroll
    for (int ks = 0; ks < 8; ++ks) {
      b[ks][0] = Bw[(size_t)((win * 8 + ks) * 8 + 0) * 64];
      b[ks][1] = Bw[(size_t)((win * 8 + ks) * 8 + 1) * 64];
    }
    // A prefetch for win+1 (contiguous 1 KiB per load)
    float4 aR[4];
    if (win < 31) {
      #pragma unroll
      for (int j = 0; j < 4; ++j)
        aR[j] = *(const float4*)(Ap + j * 8192 + (size_t)(win + 1) * 256);
    }
    // consume window from LDS
    #pragma unroll
    for (int ks = 0; ks < 8; ++ks) {
      bf16x8 af = *(const bf16x8*)
          &a_lds[cur][16 * wm + l15][ks * 32 + quad * 8];
      acc[0] = __builtin_amdgcn_mfma_f32_16x16x32_bf16(af, b[ks][0], acc[0],
                                                       0, 0, 0);
      acc[1] = __builtin_amdgcn_mfma_f32_16x16x32_bf16(af, b[ks][1], acc[1],
                                                       0, 0, 0);
    }
    // pack + stage win+1
    if (win < 31) {
      #pragma unroll
      for (int j = 0; j < 4; ++j) {
        as4[j] = fmaf(aR[j].x, aR[j].x, fmaf(aR[j].y, aR[j].y,
                 fmaf(aR[j].z, aR[j].z, fmaf(aR[j].w, aR[j].w, as4[j]))));
        *(uint2*)&a_lds[cur ^ 1][4 * w + j][lane * 4] =
            make_uint2(pk_trunc(aR[j].x, aR[j].y), pk_trunc(aR[j].z, aR[j].w));
      }
    }
    __syncthreads();
  }

  // ---- epilogue: alias staging LDS for C-park + row sums
  float (*part)[132] = (float (*)[132]) & a_lds[0][0][0];   // 32 x 132 fp32
  float* asw = (float*)&a_lds[0][0][0] + 32 * 132;          // 32 fp32

  #pragma unroll
  for (int i = 0; i < 2; ++i)
    #pragma unroll
    for (int r = 0; r < 4; ++r)
      part[16 * wm + quad * 4 + r][32 * wn + 16 * i + l15] = acc[i][r];
  #pragma unroll
  for (int j = 0; j < 4; ++j) {
    float s = as4[j];
    #pragma unroll
    for (int m = 1; m < 64; m <<= 1) s += __shfl_xor(s, m, 64);
    if (lane == 0) asw[4 * w + j] = s;
  }
  __syncthreads();

  // 16 threads per row, 8 cols each
  const int row = t >> 4, j0 = t & 15;
  float v[8];
  {
    float4 q0 = *(const float4*)&part[row][j0 * 8];
    float4 q1 = *(const float4*)&part[row][j0 * 8 + 4];
    v[0]=q0.x; v[1]=q0.y; v[2]=q0.z; v[3]=q0.w;
    v[4]=q1.x; v[5]=q1.y; v[6]=q1.z; v[7]=q1.w;
  }
  const float xss = asw[row];

  float mxss_l = 0.f; int zf = 1;
  #pragma unroll
  for (int i = 0; i < 8; ++i) { mxss_l += v[i] * v[i]; zf &= (v[i] == 0.f); }
  const float mxss = red16(mxss_l);
  zf = red16_and(zf);

  const float xn  = fmaxf(sqrtf(xss), MINN);
  const float mxn = fmaxf(sqrtf(mxss), MINN);
  float f1 = 0.f;
  if (!zf) f1 = tanhf(mxn / xn * artanh_clip(sc * xn)) / (mxn * sc);

  float yv[8];
  {
    float4 q0 = ((const float4*)yvec)[j0 * 2];
    float4 q1 = ((const float4*)yvec)[j0 * 2 + 1];
    yv[0]=q0.x; yv[1]=q0.y; yv[2]=q0.z; yv[3]=q0.w;
    yv[4]=q1.x; yv[5]=q1.y; yv[6]=q1.z; yv[7]=q1.w;
  }

  // mobius_add(f1*v, yv, c) (raw Euclidean bias per source)
  float xy_l = 0.f, y2_l = 0.f, o8[8];
  #pragma unroll
  for (int i = 0; i < 8; ++i) {
    o8[i] = f1 * v[i];
    xy_l += o8[i] * yv[i];
    y2_l += yv[i] * yv[i];
  }
  const float xy = red16(xy_l), y2 = red16(y2_l);
  const float x2 = f1 * f1 * mxss;
  const float den = fmaxf(1.0f + 2.0f * c * xy + c * c * x2 * y2, MINN);
  const float ca = (1.0f + 2.0f * c * xy + c * y2) / den;
  const float cb = (1.0f - c * x2) / den;
  float h8[8]; float hss_l = 0.f;
  #pragma unroll
  for (int i = 0; i < 8; ++i) {
    h8[i] = ca * o8[i] + cb * yv[i];
    hss_l += h8[i] * h8[i];
  }
  const float hss = red16(hss_l);
  const float hn  = fmaxf(sqrtf(hss), MINN);
  const float s2  = (hn > maxn) ? maxn / hn : 1.0f;   // proj(., c)

  // hyp_act: logmap0 -> leaky_relu -> expmap0(c) -> proj(1-c)
  const float pn = fmaxf(s2 * hn, MINN);
  const float lf = artanh_clip(sc * pn) / (pn * sc);
  float xt[8]; float uss_l = 0.f;
  #pragma unroll
  for (int i = 0; i < 8; ++i) {
    float l = lf * (s2 * h8[i]);
    xt[i] = (l >= 0.f) ? l : 0.01f * l;
    uss_l += xt[i] * xt[i];
  }
  const float uss = red16(uss_l);
  const float un  = fmaxf(sqrtf(uss), MINN);
  const float ef  = tanhf(sc * un) / (sc * un);
  const float on  = ef * un;
  const float maxn2 = 0.996f / sqrtf(1.0f - c);
  const float s3 = (on > maxn2) ? maxn2 / on : 1.0f;

  float* orow = out + (size_t)(row0 + row) * 128 + j0 * 8;
  *(float4*)orow =
      make_float4(s3*ef*xt[0], s3*ef*xt[1], s3*ef*xt[2], s3*ef*xt[3]);
  *(float4*)(orow + 4) =
      make_float4(s3*ef*xt[4], s3*ef*xt[5], s3*ef*xt[6], s3*ef*xt[7]);
}

// ---------------------------------------------------------------------------
extern "C" void kernel_launch(void* const* d_in, const int* in_sizes, int n_in,
                              void* d_out, int out_size, void* d_ws, size_t ws_size,
                              hipStream_t stream)
{
  const float* x   = (const float*)d_in[0];   // [8192,512]
  const float* adj = (const float*)d_in[1];   // [8192,8192]
  const float* cp  = (const float*)d_in[2];   // [1]
  const float* lw  = (const float*)d_in[3];   // [128,512]
  const float* lb  = (const float*)d_in[4];   // [128]
  const float* aw  = (const float*)d_in[5];   // [128,128]
  const float* ab  = (const float*)d_in[6];   // [128]
  float* out = (float*)d_out;                 // [8192,128] fp32

  char* ws = (char*)d_ws;
  unsigned short* B1sw = (unsigned short*)(ws);                  // 128 KiB
  unsigned short* B2sw = (unsigned short*)(ws + 131072);         // 32 KiB
  unsigned short* B3sw = (unsigned short*)(ws + 163840);         // 2 MiB
  float*          hb   = (float*)(ws + 2260992);                 // 512 B

  prep_kernel<<<257, 128, 0, stream>>>(lw, aw, lb, cp, B1sw, B2sw, hb);
  hyp_fused12<<<512, 256, 0, stream>>>(x, (const bf16x8*)B1sw,
                                       (const bf16x8*)B2sw, cp, hb, B3sw);
  hyp_gemm3<<<256, 512, 0, stream>>>(adj, (const bf16x8*)B3sw, cp, ab, out);
}